// Round 6
// baseline (65.027 us; speedup 1.0000x reference)
//
#include <hip/hip_runtime.h>
#include <math.h>

// Problem constants (from reference)
#define NUM_T   8      // NUM_NODE_TYPES
#define TIN     16     // 2 * NUM_NODE_TYPES
#define HID     64     // HIDDEN
#define OUTD    16     // D*D
#define LN_EPS  1e-5f

#define N_PACK_U32 12500   // ceil(100000 / 8)
#define CHUNK      4096    // edges per store-kernel block

typedef float f32x4 __attribute__((ext_vector_type(4)));

// ---------------------------------------------------------------------------
// k0: pack node types to nibbles (8/u32) AND (block 0) build the 64-entry
// (ts,tt) -> 16-float table.  ws: [0,4KB) table ; [4KB,54KB) packed.
// ---------------------------------------------------------------------------
__global__ __launch_bounds__(256) void
prep_kernel(const int* __restrict__ ntypes, int n_nodes,
            const float* __restrict__ ln_g,
            const float* __restrict__ ln_b,
            const float* __restrict__ W1,   // [16][64]
            const float* __restrict__ b1,   // [64]
            const float* __restrict__ W2,   // [64][16]
            const float* __restrict__ b2,   // [16]
            f32x4* __restrict__ table4,     // [64][4]
            unsigned int* __restrict__ packed)
{
    const int t = threadIdx.x;
    const int g = blockIdx.x * 256 + t;

    if (g < N_PACK_U32) {
        unsigned int w = 0;
        int n0 = g * 8;
        #pragma unroll
        for (int j = 0; j < 8; ++j) {
            int n = n0 + j;
            unsigned int ty = (n < n_nodes) ? (unsigned int)ntypes[n] : 0u;
            w |= (ty & 7u) << (j * 4);
        }
        packed[g] = w;
    }

    if (blockIdx.x != 0) return;

    __shared__ float sW1[TIN * HID];
    __shared__ float sW2[HID * OUTD];
    __shared__ float sb1[HID];
    __shared__ float sg[TIN], sb[TIN], sb2[OUTD];

    for (int i = t; i < TIN * HID; i += 256) sW1[i] = W1[i];
    for (int i = t; i < HID * OUTD; i += 256) sW2[i] = W2[i];
    if (t < HID) sb1[t] = b1[t];
    if (t < TIN) { sg[t] = ln_g[t]; sb[t] = ln_b[t]; }
    if (t < OUTD) sb2[t] = b2[t];
    __syncthreads();

    const int p  = t >> 2;       // pair 0..63
    const int kg = t & 3;        // k-group 0..3
    const int ts = p >> 3;
    const int tt = p & 7;

    const float mu = 2.0f / 16.0f;
    float var = 0.0f;
    #pragma unroll
    for (int j = 0; j < TIN; ++j) {
        float h = (j == ts || j == (8 + tt)) ? 1.0f : 0.0f;
        float d = h - mu;
        var += d * d;
    }
    var *= (1.0f / 16.0f);
    const float inv = rsqrtf(var + LN_EPS);

    float hn[TIN];
    #pragma unroll
    for (int j = 0; j < TIN; ++j) {
        float h = (j == ts || j == (8 + tt)) ? 1.0f : 0.0f;
        hn[j] = (h - mu) * inv * sg[j] + sb[j];
    }

    float s[OUTD];
    #pragma unroll
    for (int o = 0; o < OUTD; ++o) s[o] = 0.0f;

    const int k0 = kg * 16;
    for (int k = k0; k < k0 + 16; ++k) {
        float a = sb1[k];
        #pragma unroll
        for (int j = 0; j < TIN; ++j) a += hn[j] * sW1[j * HID + k];
        a = fmaxf(a, 0.0f);
        #pragma unroll
        for (int o = 0; o < OUTD; ++o) s[o] += a * sW2[k * OUTD + o];
    }

    #pragma unroll
    for (int o = 0; o < OUTD; ++o) {
        s[o] += __shfl_xor(s[o], 1);
        s[o] += __shfl_xor(s[o], 2);
        s[o] += sb2[o];
    }

    const int r = kg;
    float s0 = s[4*r+0], s1 = s[4*r+1], s2 = s[4*r+2], s3 = s[4*r+3];
    float m  = fmaxf(fmaxf(s0, s1), fmaxf(s2, s3));
    float e0 = expf(s0 - m), e1 = expf(s1 - m),
          e2 = expf(s2 - m), e3 = expf(s3 - m);
    float rs = 1.0f / (e0 + e1 + e2 + e3);
    f32x4 outv;
    outv.x = (r == 0 ? 1.0f : 0.0f) - e0 * rs;
    outv.y = (r == 1 ? 1.0f : 0.0f) - e1 * rs;
    outv.z = (r == 2 ? 1.0f : 0.0f) - e2 * rs;
    outv.w = (r == 3 ? 1.0f : 0.0f) - e3 * rs;
    table4[p * 4 + r] = outv;
}

// ---------------------------------------------------------------------------
// k1: per-edge pair byte.  int4 index loads (4 edges/lane), LDS nibble
// lookups, uchar4 coalesced stores.  Copy-like traffic: 25.6R + 3.2W MB.
// ---------------------------------------------------------------------------
__global__ __launch_bounds__(256) void
pair_kernel(const int* __restrict__ row,
            const int* __restrict__ col,
            const unsigned int* __restrict__ packed,
            unsigned int* __restrict__ pairs_u32,  // [E/4] uchar4
            int n_units)                            // E/4
{
    __shared__ unsigned int nt_lds[N_PACK_U32];     // 50 KB
    const int t = threadIdx.x;
    {
        const uint4* s4 = (const uint4*)packed;
        uint4* d4 = (uint4*)nt_lds;
        for (int i = t; i < N_PACK_U32 / 4; i += 256) d4[i] = s4[i];
        for (int i = (N_PACK_U32 & ~3) + t; i < N_PACK_U32; i += 256)
            nt_lds[i] = packed[i];
    }
    __syncthreads();

    const int stride = gridDim.x * 256;
    const int4* row4 = (const int4*)row;
    const int4* col4 = (const int4*)col;

    for (int u = blockIdx.x * 256 + t; u < n_units; u += stride) {
        int4 rv = row4[u];
        int4 cv = col4[u];
        int rr[4] = {rv.x, rv.y, rv.z, rv.w};
        int cc[4] = {cv.x, cv.y, cv.z, cv.w};
        unsigned int outw = 0;
        #pragma unroll
        for (int j = 0; j < 4; ++j) {
            int r = rr[j], c = cc[j];
            unsigned int tr = (nt_lds[r >> 3] >> ((r & 7) * 4)) & 7u;
            unsigned int tc = (nt_lds[c >> 3] >> ((c & 7) * 4)) & 7u;
            outw |= ((tr << 3) | tc) << (j * 8);
        }
        pairs_u32[u] = outw;
    }
}

// ---------------------------------------------------------------------------
// k2: pure store stream.  One CHUNK-edge tile per block; pair bytes + table
// staged in LDS (single vmcnt wait), then 64 iterations of
// ds_read_u8 -> ds_read_b128 -> nontemporal 16B store: no global loads in
// the hot loop, so stores issue back-to-back like the fill kernel.
// ---------------------------------------------------------------------------
__global__ __launch_bounds__(256) void
store_kernel(const unsigned int* __restrict__ pairs_u32,
             const f32x4* __restrict__ table4,   // [64][4]
             f32x4* __restrict__ out4,           // [E][4]
             int E)
{
    __shared__ f32x4 lds_table[64 * 5];          // stride-5 pad
    __shared__ unsigned char pair_lds[CHUNK];    // 4 KB

    const int t = threadIdx.x;
    {   // table (5 KB)
        int p = t >> 2, q = t & 3;
        lds_table[p * 5 + q] = table4[t];
    }
    const int base = blockIdx.x * CHUNK;
    {   // pair bytes for this chunk
        unsigned int* pl32 = (unsigned int*)pair_lds;
        const int n_units = (E + 3) >> 2;
        #pragma unroll
        for (int i = t; i < CHUNK / 4; i += 256) {
            int idx = (base >> 2) + i;
            pl32[i] = (idx < n_units) ? pairs_u32[idx] : 0u;
        }
    }
    __syncthreads();

    #pragma unroll 8
    for (int i = 0; i < (CHUNK * 4) / 256; ++i) {   // 64 iterations
        int slot = i * 256 + t;
        int el   = slot >> 2;        // local edge
        int q    = slot & 3;
        int e    = base + el;
        if (e < E) {
            int p = pair_lds[el];
            f32x4 v = lds_table[p * 5 + q];
            __builtin_nontemporal_store(v, &out4[e * 4 + q]);
        }
    }
}

// ---------------------------------------------------------------------------
// Fallback (ws too small): R5's fused scatter.
// ---------------------------------------------------------------------------
__global__ __launch_bounds__(256) void
scatter_edges_kernel(const int* __restrict__ row,
                     const int* __restrict__ col,
                     const unsigned int* __restrict__ packed,
                     const f32x4* __restrict__ table4,
                     f32x4* __restrict__ out4,
                     int E)
{
    __shared__ f32x4 lds_table[64 * 5];
    __shared__ unsigned int nt_lds[N_PACK_U32];
    const int t = threadIdx.x;
    {
        int p = t >> 2, q = t & 3;
        lds_table[p * 5 + q] = table4[t];
    }
    {
        const uint4* src4 = (const uint4*)packed;
        uint4* dst4 = (uint4*)nt_lds;
        for (int i = t; i < N_PACK_U32 / 4; i += 256) dst4[i] = src4[i];
        for (int i = (N_PACK_U32 & ~3) + t; i < N_PACK_U32; i += 256)
            nt_lds[i] = packed[i];
    }
    __syncthreads();

    const int q      = t & 3;
    const int lane_e = t >> 2;
    const int stride = gridDim.x * 64;

    for (int e = blockIdx.x * 64 + lane_e; e < E; e += stride) {
        int r = row[e];
        int c = col[e];
        unsigned int wr = nt_lds[r >> 3];
        unsigned int wc = nt_lds[c >> 3];
        int tr = (wr >> ((r & 7) * 4)) & 7;
        int tc = (wc >> ((c & 7) * 4)) & 7;
        int pair = (tr << 3) | tc;
        f32x4 v = lds_table[pair * 5 + q];
        __builtin_nontemporal_store(v, &out4[e * 4 + q]);
    }
}

// ---------------------------------------------------------------------------
extern "C" void kernel_launch(void* const* d_in, const int* in_sizes, int n_in,
                              void* d_out, int out_size, void* d_ws, size_t ws_size,
                              hipStream_t stream)
{
    // Inputs: x, edge_index, node_types, ln_g, ln_b, W1, b1, W2, b2
    const int*   edge_index = (const int*)d_in[1];
    const int*   ntypes     = (const int*)d_in[2];
    const float* ln_g       = (const float*)d_in[3];
    const float* ln_b       = (const float*)d_in[4];
    const float* W1         = (const float*)d_in[5];
    const float* b1         = (const float*)d_in[6];
    const float* W2         = (const float*)d_in[7];
    const float* b2         = (const float*)d_in[8];

    const int E = in_sizes[1] / 2;
    const int N = in_sizes[2];

    f32x4*        table4 = (f32x4*)d_ws;                          // 4 KB
    unsigned int* packed = (unsigned int*)((char*)d_ws + 4096);   // 50 KB
    unsigned int* pairs  = (unsigned int*)((char*)d_ws + 65536);  // E bytes

    const int prep_blocks = (N_PACK_U32 + 255) / 256;
    prep_kernel<<<prep_blocks, 256, 0, stream>>>(
        ntypes, N, ln_g, ln_b, W1, b1, W2, b2, table4, packed);

    if (ws_size >= (size_t)65536 + (size_t)E + 16) {
        const int n_units = (E + 3) >> 2;
        pair_kernel<<<512, 256, 0, stream>>>(
            edge_index, edge_index + E, packed, pairs, n_units);

        const int blocks = (E + CHUNK - 1) / CHUNK;
        store_kernel<<<blocks, 256, 0, stream>>>(
            pairs, table4, (f32x4*)d_out, E);
    } else {
        scatter_edges_kernel<<<512, 256, 0, stream>>>(
            edge_index, edge_index + E, packed, table4, (f32x4*)d_out, E);
    }
}

// Round 7
// 51.159 us; speedup vs baseline: 1.2711x; 1.2711x over previous
//
#include <hip/hip_runtime.h>
#include <math.h>

// Problem constants (from reference)
#define NUM_T   8      // NUM_NODE_TYPES
#define TIN     16     // 2 * NUM_NODE_TYPES
#define HID     64     // HIDDEN
#define OUTD    16     // D*D
#define LN_EPS  1e-5f

#define N_PACK_U32 12500   // ceil(100000 / 8) ; 12500 % 4 == 0

typedef float f32x4 __attribute__((ext_vector_type(4)));

// ---------------------------------------------------------------------------
// k0: pack node types to nibbles (8/u32) AND (block 0) build the 64-entry
// (ts,tt) -> 16-float table.  ws: [0,4KB) table ; [4KB,54KB) packed.
// ---------------------------------------------------------------------------
__global__ __launch_bounds__(256) void
prep_kernel(const int* __restrict__ ntypes, int n_nodes,
            const float* __restrict__ ln_g,
            const float* __restrict__ ln_b,
            const float* __restrict__ W1,   // [16][64]
            const float* __restrict__ b1,   // [64]
            const float* __restrict__ W2,   // [64][16]
            const float* __restrict__ b2,   // [16]
            f32x4* __restrict__ table4,     // [64][4]
            unsigned int* __restrict__ packed)
{
    const int t = threadIdx.x;
    const int g = blockIdx.x * 256 + t;

    if (g < N_PACK_U32) {
        unsigned int w = 0;
        int n0 = g * 8;
        #pragma unroll
        for (int j = 0; j < 8; ++j) {
            int n = n0 + j;
            unsigned int ty = (n < n_nodes) ? (unsigned int)ntypes[n] : 0u;
            w |= (ty & 7u) << (j * 4);
        }
        packed[g] = w;
    }

    if (blockIdx.x != 0) return;

    __shared__ float sW1[TIN * HID];
    __shared__ float sW2[HID * OUTD];
    __shared__ float sb1[HID];
    __shared__ float sg[TIN], sb[TIN], sb2[OUTD];

    for (int i = t; i < TIN * HID; i += 256) sW1[i] = W1[i];
    for (int i = t; i < HID * OUTD; i += 256) sW2[i] = W2[i];
    if (t < HID) sb1[t] = b1[t];
    if (t < TIN) { sg[t] = ln_g[t]; sb[t] = ln_b[t]; }
    if (t < OUTD) sb2[t] = b2[t];
    __syncthreads();

    const int p  = t >> 2;       // pair 0..63
    const int kg = t & 3;        // k-group 0..3
    const int ts = p >> 3;
    const int tt = p & 7;

    const float mu = 2.0f / 16.0f;
    float var = 0.0f;
    #pragma unroll
    for (int j = 0; j < TIN; ++j) {
        float h = (j == ts || j == (8 + tt)) ? 1.0f : 0.0f;
        float d = h - mu;
        var += d * d;
    }
    var *= (1.0f / 16.0f);
    const float inv = rsqrtf(var + LN_EPS);

    float hn[TIN];
    #pragma unroll
    for (int j = 0; j < TIN; ++j) {
        float h = (j == ts || j == (8 + tt)) ? 1.0f : 0.0f;
        hn[j] = (h - mu) * inv * sg[j] + sb[j];
    }

    float s[OUTD];
    #pragma unroll
    for (int o = 0; o < OUTD; ++o) s[o] = 0.0f;

    const int k0 = kg * 16;
    for (int k = k0; k < k0 + 16; ++k) {
        float a = sb1[k];
        #pragma unroll
        for (int j = 0; j < TIN; ++j) a += hn[j] * sW1[j * HID + k];
        a = fmaxf(a, 0.0f);
        #pragma unroll
        for (int o = 0; o < OUTD; ++o) s[o] += a * sW2[k * OUTD + o];
    }

    #pragma unroll
    for (int o = 0; o < OUTD; ++o) {
        s[o] += __shfl_xor(s[o], 1);
        s[o] += __shfl_xor(s[o], 2);
        s[o] += sb2[o];
    }

    const int r = kg;
    float s0 = s[4*r+0], s1 = s[4*r+1], s2 = s[4*r+2], s3 = s[4*r+3];
    float m  = fmaxf(fmaxf(s0, s1), fmaxf(s2, s3));
    float e0 = expf(s0 - m), e1 = expf(s1 - m),
          e2 = expf(s2 - m), e3 = expf(s3 - m);
    float rs = 1.0f / (e0 + e1 + e2 + e3);
    f32x4 outv;
    outv.x = (r == 0 ? 1.0f : 0.0f) - e0 * rs;
    outv.y = (r == 1 ? 1.0f : 0.0f) - e1 * rs;
    outv.z = (r == 2 ? 1.0f : 0.0f) - e2 * rs;
    outv.w = (r == 3 ? 1.0f : 0.0f) - e3 * rs;
    table4[p * 4 + r] = outv;
}

// ---------------------------------------------------------------------------
// k1: scatter, 1024-thread blocks.
// LDS = 50KB nibbles + 5KB padded table -> 2 blocks/CU = 32 waves/CU (100%
// occupancy; R5's 256-thread version was stuck at 8 waves/CU).
// Per wave-iteration (64 edges):
//   Phase 1: lane i loads row/col for edge base+i (coalesced 256B loads,
//            one load pair per edge instead of 4x redundant).
//   Phase 2: 4 shfl-redistributed steps; each step is one fully-coalesced
//            1 KB wave store (plain stores: L2 write-aggregation, same as
//            the 6.9 TB/s fill kernels; nt hint dropped deliberately).
// ---------------------------------------------------------------------------
__global__ __launch_bounds__(1024) void
scatter_edges_kernel(const int* __restrict__ row,
                     const int* __restrict__ col,
                     const unsigned int* __restrict__ packed, // [N_PACK_U32]
                     const f32x4* __restrict__ table4,        // [64][4]
                     f32x4* __restrict__ out4,                // [E][4]
                     int E)
{
    __shared__ f32x4 lds_table[64 * 5];              // stride-5 pad (bank fix)
    __shared__ unsigned int nt_lds[N_PACK_U32];      // 50 KB packed nibbles

    const int t = threadIdx.x;

    if (t < 256) {   // stage table (5 KB)
        int p = t >> 2, q = t & 3;
        lds_table[p * 5 + q] = table4[t];
    }
    {   // stage packed types (50 KB) with uint4 loads; 12500/4 = 3125 exact
        const uint4* s4 = (const uint4*)packed;
        uint4* d4 = (uint4*)nt_lds;
        for (int i = t; i < N_PACK_U32 / 4; i += 1024) d4[i] = s4[i];
    }
    __syncthreads();

    const int lane = t & 63;
    const int wid  = t >> 6;             // wave in block, 0..15
    const int q    = lane & 3;           // output quad
    const int sub  = lane >> 2;          // 0..15
    const int stride = gridDim.x * 1024; // 16 waves * 64 edges per block

    for (int base = blockIdx.x * 1024 + wid * 64; base < E; base += stride) {
        // Phase 1: one edge per lane.
        int e  = base + lane;
        int ec = (e < E) ? e : (E - 1);
        int r = row[ec];
        int c = col[ec];
        unsigned int tr = (nt_lds[r >> 3] >> ((r & 7) * 4)) & 7u;
        unsigned int tc = (nt_lds[c >> 3] >> ((c & 7) * 4)) & 7u;
        int pair = (int)((tr << 3) | tc);

        // Phase 2: four independent coalesced 1 KB wave stores.
        #pragma unroll
        for (int j = 0; j < 4; ++j) {
            int src = j * 16 + sub;
            int pj  = __shfl(pair, src, 64);
            int ej  = base + src;
            if (ej < E) {
                out4[ej * 4 + q] = lds_table[pj * 5 + q];
            }
        }
    }
}

// ---------------------------------------------------------------------------
extern "C" void kernel_launch(void* const* d_in, const int* in_sizes, int n_in,
                              void* d_out, int out_size, void* d_ws, size_t ws_size,
                              hipStream_t stream)
{
    // Inputs: x, edge_index, node_types, ln_g, ln_b, W1, b1, W2, b2
    const int*   edge_index = (const int*)d_in[1];   // [2][E] int32
    const int*   ntypes     = (const int*)d_in[2];   // [N] int32
    const float* ln_g       = (const float*)d_in[3];
    const float* ln_b       = (const float*)d_in[4];
    const float* W1         = (const float*)d_in[5];
    const float* b1         = (const float*)d_in[6];
    const float* W2         = (const float*)d_in[7];
    const float* b2         = (const float*)d_in[8];

    const int E = in_sizes[1] / 2;
    const int N = in_sizes[2];

    f32x4*        table4 = (f32x4*)d_ws;                        // 4 KB
    unsigned int* packed = (unsigned int*)((char*)d_ws + 4096); // 50 KB

    const int prep_blocks = (N_PACK_U32 + 255) / 256;  // 49
    prep_kernel<<<prep_blocks, 256, 0, stream>>>(
        ntypes, N, ln_g, ln_b, W1, b1, W2, b2, table4, packed);

    const int blocks = 512;   // 2 blocks/CU (55KB LDS), 32 waves/CU
    scatter_edges_kernel<<<blocks, 1024, 0, stream>>>(
        edge_index, edge_index + E, packed,
        table4, (f32x4*)d_out, E);
}

// Round 8
// 46.227 us; speedup vs baseline: 1.4067x; 1.1067x over previous
//
#include <hip/hip_runtime.h>
#include <math.h>

// Problem constants (from reference)
#define NUM_T   8      // NUM_NODE_TYPES
#define TIN     16     // 2 * NUM_NODE_TYPES
#define HID     64     // HIDDEN
#define OUTD    16     // D*D
#define LN_EPS  1e-5f

#define N_PACK_U32  12500   // ceil(100000 / 8) ; 12500 % 4 == 0
#define PACK_BLOCKS 49      // ceil(12500 / 256)

typedef float f32x4 __attribute__((ext_vector_type(4)));

// ---------------------------------------------------------------------------
// k0: blocks [0,49): pack node types to nibbles (8 per u32).
//     blocks [49,113): one (ts,tt) pair per block; one wave computes the
//     16-float output row straight from L2 (no LDS: the R7 version's 2048
//     wave-level ds_read_b32 serialized ~5us on a single CU's LDS pipe).
// ws: [0,4KB) table ; [4KB,54KB) packed nibbles.
// ---------------------------------------------------------------------------
__global__ __launch_bounds__(256) void
prep_kernel(const int* __restrict__ ntypes, int n_nodes,
            const float* __restrict__ ln_g,
            const float* __restrict__ ln_b,
            const float* __restrict__ W1,   // [16][64]
            const float* __restrict__ b1,   // [64]
            const float* __restrict__ W2,   // [64][16]
            const float* __restrict__ b2,   // [16]
            f32x4* __restrict__ table4,     // [64][4]
            unsigned int* __restrict__ packed)
{
    const int t = threadIdx.x;

    if (blockIdx.x < PACK_BLOCKS) {
        // ---- packing ----
        const int g = blockIdx.x * 256 + t;
        if (g < N_PACK_U32) {
            unsigned int w = 0;
            int n0 = g * 8;
            #pragma unroll
            for (int j = 0; j < 8; ++j) {
                int n = n0 + j;
                unsigned int ty = (n < n_nodes) ? (unsigned int)ntypes[n] : 0u;
                w |= (ty & 7u) << (j * 4);
            }
            packed[g] = w;
        }
        return;
    }

    // ---- table build: one pair per block, lanes 0..63 = k ----
    if (t >= 64) return;
    const int p  = blockIdx.x - PACK_BLOCKS;   // 0..63
    const int ts = p >> 3;
    const int tt = p & 7;
    const int k  = t;

    const float mu = 2.0f / 16.0f;
    float var = 0.0f;
    #pragma unroll
    for (int j = 0; j < TIN; ++j) {
        float h = (j == ts || j == (8 + tt)) ? 1.0f : 0.0f;
        float d = h - mu;
        var += d * d;
    }
    var *= (1.0f / 16.0f);
    const float inv = rsqrtf(var + LN_EPS);

    // a_k = b1[k] + sum_j hn[j] * W1[j][k]   (W1 column reads coalesced)
    float a = b1[k];
    #pragma unroll
    for (int j = 0; j < TIN; ++j) {
        float h  = (j == ts || j == (8 + tt)) ? 1.0f : 0.0f;
        float hn = (h - mu) * inv * ln_g[j] + ln_b[j];
        a += hn * W1[j * HID + k];
    }
    a = fmaxf(a, 0.0f);

    // s_o = sum_k a_k * W2[k][o]  : per-lane partial then 6-step shfl tree.
    const f32x4* W2v = (const f32x4*)W2;   // [64][4]
    f32x4 w0 = W2v[k * 4 + 0], w1 = W2v[k * 4 + 1],
          w2 = W2v[k * 4 + 2], w3 = W2v[k * 4 + 3];

    float s[OUTD];
    #pragma unroll
    for (int i = 0; i < 4; ++i) {
        s[0 + i]  = a * w0[i];
        s[4 + i]  = a * w1[i];
        s[8 + i]  = a * w2[i];
        s[12 + i] = a * w3[i];
    }
    #pragma unroll
    for (int o = 0; o < OUTD; ++o) {
        s[o] += __shfl_xor(s[o], 1);
        s[o] += __shfl_xor(s[o], 2);
        s[o] += __shfl_xor(s[o], 4);
        s[o] += __shfl_xor(s[o], 8);
        s[o] += __shfl_xor(s[o], 16);
        s[o] += __shfl_xor(s[o], 32);
        s[o] += b2[o];
    }

    // Lanes 0..3 finish softmax row r = lane, then I - P.
    if (t < 4) {
        const int r = t;
        float s0 = s[4*r+0], s1 = s[4*r+1], s2 = s[4*r+2], s3 = s[4*r+3];
        float m  = fmaxf(fmaxf(s0, s1), fmaxf(s2, s3));
        float e0 = expf(s0 - m), e1 = expf(s1 - m),
              e2 = expf(s2 - m), e3 = expf(s3 - m);
        float rs = 1.0f / (e0 + e1 + e2 + e3);
        f32x4 outv;
        outv.x = (r == 0 ? 1.0f : 0.0f) - e0 * rs;
        outv.y = (r == 1 ? 1.0f : 0.0f) - e1 * rs;
        outv.z = (r == 2 ? 1.0f : 0.0f) - e2 * rs;
        outv.w = (r == 3 ? 1.0f : 0.0f) - e3 * rs;
        table4[p * 4 + r] = outv;
    }
}

// ---------------------------------------------------------------------------
// k1: scatter, 1024-thread blocks, 2 blocks/CU (55 KB LDS) = 32 waves/CU.
// Explicit 1-deep software pipeline per wave-iteration (64 edges):
//   top:    issue NEXT iteration's row/col loads (independent of stores)
//   middle: 4 shfl-redistributed coalesced 1 KB wave stores using the pair
//           computed LAST iteration
//   bottom: nibble-lookup pair for the prefetched indices
// This breaks the load(900cy) -> gather -> shfl -> ds_read -> store serial
// chain that R3/R5/R7 all shared.
// ---------------------------------------------------------------------------
__global__ __launch_bounds__(1024) void
scatter_edges_kernel(const int* __restrict__ row,
                     const int* __restrict__ col,
                     const unsigned int* __restrict__ packed, // [N_PACK_U32]
                     const f32x4* __restrict__ table4,        // [64][4]
                     f32x4* __restrict__ out4,                // [E][4]
                     int E)
{
    __shared__ f32x4 lds_table[64 * 5];              // stride-5 pad (bank fix)
    __shared__ unsigned int nt_lds[N_PACK_U32];      // 50 KB packed nibbles

    const int t = threadIdx.x;

    if (t < 256) {   // stage table (5 KB)
        int p = t >> 2, q = t & 3;
        lds_table[p * 5 + q] = table4[t];
    }
    {   // stage packed types (50 KB); 12500/4 = 3125 exact
        const uint4* s4 = (const uint4*)packed;
        uint4* d4 = (uint4*)nt_lds;
        for (int i = t; i < N_PACK_U32 / 4; i += 1024) d4[i] = s4[i];
    }
    __syncthreads();

    const int lane = t & 63;
    const int wid  = t >> 6;             // wave in block, 0..15
    const int q    = lane & 3;           // output quad
    const int sub  = lane >> 2;          // 0..15
    const int stride = gridDim.x * 1024; // 16 waves * 64 edges per block

    int base = blockIdx.x * 1024 + wid * 64;
    if (base >= E) return;

    // Prologue: load + pair for the first chunk.
    int pair;
    {
        int e  = base + lane;
        int ec = (e < E) ? e : (E - 1);
        int r = row[ec];
        int c = col[ec];
        unsigned int tr = (nt_lds[r >> 3] >> ((r & 7) * 4)) & 7u;
        unsigned int tc = (nt_lds[c >> 3] >> ((c & 7) * 4)) & 7u;
        pair = (int)((tr << 3) | tc);
    }

    while (base < E) {
        const int nbase = base + stride;
        const bool have_next = (nbase < E);

        // top: prefetch next chunk's indices
        int rn = 0, cn = 0;
        if (have_next) {
            int en  = nbase + lane;
            int enc = (en < E) ? en : (E - 1);
            rn = row[enc];
            cn = col[enc];
        }

        // middle: four independent coalesced 1 KB wave stores
        #pragma unroll
        for (int j = 0; j < 4; ++j) {
            int src = j * 16 + sub;
            int pj  = __shfl(pair, src, 64);
            int ej  = base + src;
            if (ej < E) {
                out4[ej * 4 + q] = lds_table[pj * 5 + q];
            }
        }

        // bottom: pair for the prefetched chunk
        if (have_next) {
            unsigned int tr = (nt_lds[rn >> 3] >> ((rn & 7) * 4)) & 7u;
            unsigned int tc = (nt_lds[cn >> 3] >> ((cn & 7) * 4)) & 7u;
            pair = (int)((tr << 3) | tc);
        }
        base = nbase;
    }
}

// ---------------------------------------------------------------------------
extern "C" void kernel_launch(void* const* d_in, const int* in_sizes, int n_in,
                              void* d_out, int out_size, void* d_ws, size_t ws_size,
                              hipStream_t stream)
{
    // Inputs: x, edge_index, node_types, ln_g, ln_b, W1, b1, W2, b2
    const int*   edge_index = (const int*)d_in[1];   // [2][E] int32
    const int*   ntypes     = (const int*)d_in[2];   // [N] int32
    const float* ln_g       = (const float*)d_in[3];
    const float* ln_b       = (const float*)d_in[4];
    const float* W1         = (const float*)d_in[5];
    const float* b1         = (const float*)d_in[6];
    const float* W2         = (const float*)d_in[7];
    const float* b2         = (const float*)d_in[8];

    const int E = in_sizes[1] / 2;
    const int N = in_sizes[2];

    f32x4*        table4 = (f32x4*)d_ws;                        // 4 KB
    unsigned int* packed = (unsigned int*)((char*)d_ws + 4096); // 50 KB

    prep_kernel<<<PACK_BLOCKS + 64, 256, 0, stream>>>(
        ntypes, N, ln_g, ln_b, W1, b1, W2, b2, table4, packed);

    const int blocks = 512;   // 2 blocks/CU (55KB LDS), 32 waves/CU
    scatter_edges_kernel<<<blocks, 1024, 0, stream>>>(
        edge_index, edge_index + E, packed,
        table4, (f32x4*)d_out, E);
}

// Round 9
// 45.974 us; speedup vs baseline: 1.4144x; 1.0055x over previous
//
#include <hip/hip_runtime.h>
#include <math.h>

// Problem constants (from reference)
#define NUM_T   8      // NUM_NODE_TYPES
#define TIN     16     // 2 * NUM_NODE_TYPES
#define HID     64     // HIDDEN
#define OUTD    16     // D*D
#define LN_EPS  1e-5f

#define N_PACK_U32  12500   // ceil(100000 / 8) ; 12500 % 4 == 0
#define PACK_BLOCKS 49      // ceil(12500 / 256)

typedef float f32x4 __attribute__((ext_vector_type(4)));

// ---------------------------------------------------------------------------
// k0: blocks [0,49): pack node types to nibbles (8 per u32).
//     blocks [49,113): one (ts,tt) pair per block; one wave computes the
//     16-float output row straight from L2 (coalesced, no LDS).
// ws: [0,4KB) table ; [4KB,54KB) packed nibbles.
// ---------------------------------------------------------------------------
__global__ __launch_bounds__(256) void
prep_kernel(const int* __restrict__ ntypes, int n_nodes,
            const float* __restrict__ ln_g,
            const float* __restrict__ ln_b,
            const float* __restrict__ W1,   // [16][64]
            const float* __restrict__ b1,   // [64]
            const float* __restrict__ W2,   // [64][16]
            const float* __restrict__ b2,   // [16]
            f32x4* __restrict__ table4,     // [64][4]
            unsigned int* __restrict__ packed)
{
    const int t = threadIdx.x;

    if (blockIdx.x < PACK_BLOCKS) {
        const int g = blockIdx.x * 256 + t;
        if (g < N_PACK_U32) {
            unsigned int w = 0;
            int n0 = g * 8;
            #pragma unroll
            for (int j = 0; j < 8; ++j) {
                int n = n0 + j;
                unsigned int ty = (n < n_nodes) ? (unsigned int)ntypes[n] : 0u;
                w |= (ty & 7u) << (j * 4);
            }
            packed[g] = w;
        }
        return;
    }

    // ---- table build: one pair per block, lanes 0..63 = k ----
    if (t >= 64) return;
    const int p  = blockIdx.x - PACK_BLOCKS;   // 0..63
    const int ts = p >> 3;
    const int tt = p & 7;
    const int k  = t;

    const float mu = 2.0f / 16.0f;
    float var = 0.0f;
    #pragma unroll
    for (int j = 0; j < TIN; ++j) {
        float h = (j == ts || j == (8 + tt)) ? 1.0f : 0.0f;
        float d = h - mu;
        var += d * d;
    }
    var *= (1.0f / 16.0f);
    const float inv = rsqrtf(var + LN_EPS);

    float a = b1[k];
    #pragma unroll
    for (int j = 0; j < TIN; ++j) {
        float h  = (j == ts || j == (8 + tt)) ? 1.0f : 0.0f;
        float hn = (h - mu) * inv * ln_g[j] + ln_b[j];
        a += hn * W1[j * HID + k];
    }
    a = fmaxf(a, 0.0f);

    const f32x4* W2v = (const f32x4*)W2;   // [64][4]
    f32x4 w0 = W2v[k * 4 + 0], w1 = W2v[k * 4 + 1],
          w2 = W2v[k * 4 + 2], w3 = W2v[k * 4 + 3];

    float s[OUTD];
    #pragma unroll
    for (int i = 0; i < 4; ++i) {
        s[0 + i]  = a * w0[i];
        s[4 + i]  = a * w1[i];
        s[8 + i]  = a * w2[i];
        s[12 + i] = a * w3[i];
    }
    #pragma unroll
    for (int o = 0; o < OUTD; ++o) {
        s[o] += __shfl_xor(s[o], 1);
        s[o] += __shfl_xor(s[o], 2);
        s[o] += __shfl_xor(s[o], 4);
        s[o] += __shfl_xor(s[o], 8);
        s[o] += __shfl_xor(s[o], 16);
        s[o] += __shfl_xor(s[o], 32);
        s[o] += b2[o];
    }

    if (t < 4) {
        const int r = t;
        float s0 = s[4*r+0], s1 = s[4*r+1], s2 = s[4*r+2], s3 = s[4*r+3];
        float m  = fmaxf(fmaxf(s0, s1), fmaxf(s2, s3));
        float e0 = expf(s0 - m), e1 = expf(s1 - m),
              e2 = expf(s2 - m), e3 = expf(s3 - m);
        float rs = 1.0f / (e0 + e1 + e2 + e3);
        f32x4 outv;
        outv.x = (r == 0 ? 1.0f : 0.0f) - e0 * rs;
        outv.y = (r == 1 ? 1.0f : 0.0f) - e1 * rs;
        outv.z = (r == 2 ? 1.0f : 0.0f) - e2 * rs;
        outv.w = (r == 3 ? 1.0f : 0.0f) - e3 * rs;
        table4[p * 4 + r] = outv;
    }
}

// ---------------------------------------------------------------------------
// k1: scatter, 1024-thread blocks, 2 blocks/CU (55 KB LDS) = 32 waves/CU.
// 1-deep software pipeline (prefetch next chunk's indices before stores).
// EXACT=true (E % 64 == 0, the actual shape): zero predication in the hot
// loop -> straight-line global_store_dwordx4 with folded offsets, no
// exec-mask VALU. Generic path kept for safety.
// ---------------------------------------------------------------------------
template <bool EXACT>
__global__ __launch_bounds__(1024) void
scatter_edges_kernel(const int* __restrict__ row,
                     const int* __restrict__ col,
                     const unsigned int* __restrict__ packed, // [N_PACK_U32]
                     const f32x4* __restrict__ table4,        // [64][4]
                     f32x4* __restrict__ out4,                // [E][4]
                     int E)
{
    __shared__ f32x4 lds_table[64 * 5];              // stride-5 pad (bank fix)
    __shared__ unsigned int nt_lds[N_PACK_U32];      // 50 KB packed nibbles

    const int t = threadIdx.x;

    if (t < 256) {   // stage table (5 KB)
        int p = t >> 2, q = t & 3;
        lds_table[p * 5 + q] = table4[t];
    }
    {   // stage packed types (50 KB); 12500/4 = 3125 exact
        const uint4* s4 = (const uint4*)packed;
        uint4* d4 = (uint4*)nt_lds;
        for (int i = t; i < N_PACK_U32 / 4; i += 1024) d4[i] = s4[i];
    }
    __syncthreads();

    const int lane = t & 63;
    const int wid  = t >> 6;             // wave in block, 0..15
    const int q    = lane & 3;           // output quad
    const int sub  = lane >> 2;          // 0..15
    const int stride = gridDim.x * 1024; // 16 waves * 64 edges per block

    int base = blockIdx.x * 1024 + wid * 64;
    if (base >= E) return;

    // Prologue: load + pair for the first chunk.
    int pair;
    {
        int e  = base + lane;
        int ec = EXACT ? e : ((e < E) ? e : (E - 1));
        int r = row[ec];
        int c = col[ec];
        unsigned int tr = (nt_lds[r >> 3] >> ((r & 7) * 4)) & 7u;
        unsigned int tc = (nt_lds[c >> 3] >> ((c & 7) * 4)) & 7u;
        pair = (int)((tr << 3) | tc);
    }

    while (base < E) {
        const int nbase = base + stride;
        const bool have_next = (nbase < E);

        // top: prefetch next chunk's indices (hidden under store issuance)
        int rn = 0, cn = 0;
        if (have_next) {
            int en  = nbase + lane;
            int enc = EXACT ? en : ((en < E) ? en : (E - 1));
            rn = row[enc];
            cn = col[enc];
        }

        // middle: four independent coalesced 1 KB wave stores
        #pragma unroll
        for (int j = 0; j < 4; ++j) {
            int src = j * 16 + sub;
            int pj  = __shfl(pair, src, 64);
            if (EXACT) {
                out4[(base + src) * 4 + q] = lds_table[pj * 5 + q];
            } else {
                int ej = base + src;
                if (ej < E) out4[ej * 4 + q] = lds_table[pj * 5 + q];
            }
        }

        // bottom: pair for the prefetched chunk
        if (have_next) {
            unsigned int tr = (nt_lds[rn >> 3] >> ((rn & 7) * 4)) & 7u;
            unsigned int tc = (nt_lds[cn >> 3] >> ((cn & 7) * 4)) & 7u;
            pair = (int)((tr << 3) | tc);
        }
        base = nbase;
    }
}

// ---------------------------------------------------------------------------
extern "C" void kernel_launch(void* const* d_in, const int* in_sizes, int n_in,
                              void* d_out, int out_size, void* d_ws, size_t ws_size,
                              hipStream_t stream)
{
    // Inputs: x, edge_index, node_types, ln_g, ln_b, W1, b1, W2, b2
    const int*   edge_index = (const int*)d_in[1];   // [2][E] int32
    const int*   ntypes     = (const int*)d_in[2];   // [N] int32
    const float* ln_g       = (const float*)d_in[3];
    const float* ln_b       = (const float*)d_in[4];
    const float* W1         = (const float*)d_in[5];
    const float* b1         = (const float*)d_in[6];
    const float* W2         = (const float*)d_in[7];
    const float* b2         = (const float*)d_in[8];

    const int E = in_sizes[1] / 2;
    const int N = in_sizes[2];

    f32x4*        table4 = (f32x4*)d_ws;                        // 4 KB
    unsigned int* packed = (unsigned int*)((char*)d_ws + 4096); // 50 KB

    prep_kernel<<<PACK_BLOCKS + 64, 256, 0, stream>>>(
        ntypes, N, ln_g, ln_b, W1, b1, W2, b2, table4, packed);

    const int blocks = 512;   // 2 blocks/CU (55KB LDS), 32 waves/CU
    if ((E & 63) == 0) {
        scatter_edges_kernel<true><<<blocks, 1024, 0, stream>>>(
            edge_index, edge_index + E, packed, table4, (f32x4*)d_out, E);
    } else {
        scatter_edges_kernel<false><<<blocks, 1024, 0, stream>>>(
            edge_index, edge_index + E, packed, table4, (f32x4*)d_out, E);
    }
}